// Round 2
// baseline (388.713 us; speedup 1.0000x reference)
//
#include <hip/hip_runtime.h>

typedef _Float16 f16;
typedef _Float16 f16x4 __attribute__((ext_vector_type(4)));
typedef _Float16 f16x8 __attribute__((ext_vector_type(8)));
typedef float f32x4 __attribute__((ext_vector_type(4)));
typedef unsigned int u32;

// Problem dims (fixed by setup_inputs)
#define NB   8
#define SEQ  2048
#define DQ_  512
#define DKV_ 768
#define HD_  512

__device__ __forceinline__ void gll16(const void* g, void* l) {
  __builtin_amdgcn_global_load_lds(
      (const __attribute__((address_space(1))) u32*)g,
      (__attribute__((address_space(3))) u32*)l, 16, 0, 0);
}

// ---------------- K0a: straight f32 -> f16 cast (vectorized) ----------------
__global__ __launch_bounds__(256) void cast_f2h(const float* __restrict__ in,
                                                f16* __restrict__ out, int n4) {
  int i = blockIdx.x * 256 + threadIdx.x;
  if (i >= n4) return;
  float4 v = ((const float4*)in)[i];
  f16x4 o;
  o[0] = (f16)v.x; o[1] = (f16)v.y; o[2] = (f16)v.z; o[3] = (f16)v.w;
  ((f16x4*)out)[i] = o;
}

// ---------------- K0b: transposing f32 -> f16 cast for weights ----------------
// in: [K][N] f32, out: [N][K] f16
__global__ __launch_bounds__(256) void cast_transpose(const float* __restrict__ in,
                                                      f16* __restrict__ out,
                                                      int K, int N) {
  int i = blockIdx.x * 256 + threadIdx.x;
  if (i >= K * N) return;
  int n = i / K, k = i % K;
  out[i] = (f16)in[k * N + n];
}

// ---------------- K1: fused GEMM + LayerNorm ----------------
// Block: 512 thr (8 waves). Tile: 64 rows x 512 cols (full row -> in-block LN).
// Wave w owns cols [64w, 64w+64). BK=32, mfma 16x16x32 f16, f32 accum.
// proj 2 (v) writes output TRANSPOSED per batch: vt[b][c][l].
__global__ __launch_bounds__(512) void proj_ln(
    const f16* __restrict__ xq, const f16* __restrict__ xkv,
    const f16* __restrict__ wqt, const f16* __restrict__ wkt, const f16* __restrict__ wvt,
    const float* __restrict__ bq, const float* __restrict__ gq, const float* __restrict__ beq,
    const float* __restrict__ bk, const float* __restrict__ gk, const float* __restrict__ bek,
    const float* __restrict__ bv, const float* __restrict__ gv, const float* __restrict__ bev,
    f16* __restrict__ outq, f16* __restrict__ outk, f16* __restrict__ outvt)
{
  // LDS union: staging (Xs 4KB + Wts 32KB = 36KB) reused as transpose buffer
  // (256 cols x stride 72 halves = 36KB exactly); stats region separate.
  __shared__ char smem[36864 + 4096 + 512];
  f16* Xs    = (f16*)smem;              // [64][32]
  f16* Wts   = (f16*)(smem + 4096);     // [512][32]  (Wt rows = output cols)
  f16* trans = (f16*)smem;              // [256][72]  (epilogue reuse)
  float* red = (float*)(smem + 36864);  // [64][8][2]
  float* mus = (float*)(smem + 36864 + 4096); // [64]
  float* rss = mus + 64;                      // [64]

  const int proj = blockIdx.x >> 8;
  const int tile = blockIdx.x & 255;
  const f16* X; const f16* Wt; const float *bias, *gam, *bet; f16* out; int KD;
  if (proj == 0)      { X = xq;  Wt = wqt; bias = bq; gam = gq; bet = beq; out = outq;  KD = 512; }
  else if (proj == 1) { X = xkv; Wt = wkt; bias = bk; gam = gk; bet = bek; out = outk;  KD = 768; }
  else                { X = xkv; Wt = wvt; bias = bv; gam = gv; bet = bev; out = outvt; KD = 768; }

  const int row0 = tile * 64;
  const int tid = threadIdx.x;
  const int w = tid >> 6;
  const int lane = tid & 63;
  const int g = lane >> 4, tt = lane & 15;

  f32x4 acc[4][4] = {};

  const int nk = KD >> 5;
  for (int kt = 0; kt < nk; ++kt) {
    const int k0 = kt * 32;
    if (tid < 256) {                       // stage X tile [64][32]
      int r = tid >> 2, kk = (tid & 3) * 8;
      gll16(X + (size_t)(row0 + r) * KD + k0 + kk, (char*)Xs + (tid >> 6) * 1024);
    }
    #pragma unroll
    for (int i = 0; i < 4; ++i) {          // stage Wt tile [512][32]
      int e = i * 512 + tid;
      int n = e >> 2, kk = (tid & 3) * 8;
      gll16(Wt + (size_t)n * KD + k0 + kk, (char*)Wts + i * 8192 + w * 1024);
    }
    __syncthreads();
    f16x8 af[4];
    #pragma unroll
    for (int m = 0; m < 4; ++m)
      af[m] = *(const f16x8*)&Xs[(m * 16 + tt) * 32 + g * 8];
    #pragma unroll
    for (int n = 0; n < 4; ++n) {
      f16x8 bf = *(const f16x8*)&Wts[(w * 64 + n * 16 + tt) * 32 + g * 8];
      #pragma unroll
      for (int m = 0; m < 4; ++m)
        acc[m][n] = __builtin_amdgcn_mfma_f32_16x16x32_f16(af[m], bf, acc[m][n], 0, 0, 0);
    }
    __syncthreads();
  }

  // ---- epilogue: bias add + LayerNorm stats (f32) ----
  float bias4[4], gam4[4], bet4[4];
  #pragma unroll
  for (int n = 0; n < 4; ++n) {
    int c = w * 64 + n * 16 + tt;
    bias4[n] = bias[c]; gam4[n] = gam[c]; bet4[n] = bet[c];
  }
  float rsum[4][4], rsq[4][4];
  #pragma unroll
  for (int m = 0; m < 4; ++m)
    #pragma unroll
    for (int j = 0; j < 4; ++j) { rsum[m][j] = 0.f; rsq[m][j] = 0.f; }
  #pragma unroll
  for (int m = 0; m < 4; ++m)
    #pragma unroll
    for (int n = 0; n < 4; ++n)
      #pragma unroll
      for (int j = 0; j < 4; ++j) {
        float h = acc[m][n][j] + bias4[n];
        acc[m][n][j] = h;
        rsum[m][j] += h; rsq[m][j] += h * h;
      }
  // reduce across the 16 lanes sharing each row (lane bits 0..3)
  #pragma unroll
  for (int mk = 1; mk < 16; mk <<= 1)
    #pragma unroll
    for (int m = 0; m < 4; ++m)
      #pragma unroll
      for (int j = 0; j < 4; ++j) {
        rsum[m][j] += __shfl_xor(rsum[m][j], mk);
        rsq[m][j]  += __shfl_xor(rsq[m][j], mk);
      }
  if (tt == 0) {
    #pragma unroll
    for (int m = 0; m < 4; ++m)
      #pragma unroll
      for (int j = 0; j < 4; ++j) {
        int r = m * 16 + g * 4 + j;
        red[(r * 8 + w) * 2 + 0] = rsum[m][j];
        red[(r * 8 + w) * 2 + 1] = rsq[m][j];
      }
  }
  __syncthreads();
  if (tid < 64) {   // cross-wave combine: one thread per row
    float s = 0.f, sq = 0.f;
    #pragma unroll
    for (int w2 = 0; w2 < 8; ++w2) {
      s  += red[(tid * 8 + w2) * 2 + 0];
      sq += red[(tid * 8 + w2) * 2 + 1];
    }
    float mu = s * (1.f / 512.f);
    float var = sq * (1.f / 512.f) - mu * mu;
    mus[tid] = mu;
    rss[tid] = rsqrtf(var + 1e-5f);
  }
  __syncthreads();
  #pragma unroll
  for (int m = 0; m < 4; ++m)
    #pragma unroll
    for (int j = 0; j < 4; ++j) {
      int r = m * 16 + g * 4 + j;
      float mu = mus[r], rs = rss[r];
      #pragma unroll
      for (int n = 0; n < 4; ++n)
        acc[m][n][j] = (acc[m][n][j] - mu) * rs * gam4[n] + bet4[n];
    }

  if (proj != 2) {
    // straight f16 store: out[row][col]
    #pragma unroll
    for (int m = 0; m < 4; ++m)
      #pragma unroll
      for (int j = 0; j < 4; ++j) {
        int r = row0 + m * 16 + g * 4 + j;
        #pragma unroll
        for (int n = 0; n < 4; ++n)
          out[(size_t)r * 512 + w * 64 + n * 16 + tt] = (f16)acc[m][n][j];
      }
  } else {
    // transposed store via LDS: vt[b][c][l], two 256-col chunks
    const int bch = row0 >> 11, l0 = row0 & 2047;
    __syncthreads();
    for (int half = 0; half < 2; ++half) {
      if ((w >> 2) == half) {
        #pragma unroll
        for (int m = 0; m < 4; ++m)
          #pragma unroll
          for (int n = 0; n < 4; ++n)
            #pragma unroll
            for (int j = 0; j < 4; ++j)
              trans[((w & 3) * 64 + n * 16 + tt) * 72 + (m * 16 + g * 4 + j)] =
                  (f16)acc[m][n][j];
      }
      __syncthreads();
      {
        int c = tid >> 1, ii = tid & 1;
        size_t gb = (size_t)bch * (512 * 2048) + (size_t)(half * 256 + c) * 2048
                    + l0 + ii * 32;
        #pragma unroll
        for (int q2 = 0; q2 < 4; ++q2)
          *(f16x8*)&out[gb + q2 * 8] = *(const f16x8*)&trans[c * 72 + ii * 32 + q2 * 8];
      }
      __syncthreads();
    }
  }
}

// ---------------- K2/K4: batched NT GEMM (m97 structure) ----------------
// C[b][m][n] = sum_k A[b][m][k] * Bt[b][n][k]  (+ resid), lda = ldb = K.
// 128x128 tile, BK=32, 4 waves in 2x2, mfma 16x16x32 f16.
// CT = output element type (f16 for S, float for final out).
template <bool RESID, typename CT>
__global__ __launch_bounds__(256) void gemm_nt(
    const f16* __restrict__ A, const f16* __restrict__ Bt,
    CT* __restrict__ C, const float* __restrict__ resid,
    int K, int tilesM, int tilesN, int N,
    size_t sA, size_t sB, size_t sC)
{
  __shared__ f16 As[128 * 32];
  __shared__ f16 Bs[128 * 32];
  const int bpb = tilesM * tilesN;
  const int b = blockIdx.x / bpb;
  const int t = blockIdx.x % bpb;
  const int tm = t % tilesM, tn = t / tilesM;
  const f16* Ab  = A  + (size_t)b * sA + (size_t)tm * 128 * K;
  const f16* Btb = Bt + (size_t)b * sB + (size_t)tn * 128 * K;
  const int tid = threadIdx.x, w = tid >> 6, lane = tid & 63;
  const int wr = w >> 1, wc = w & 1;
  const int g = lane >> 4, tt = lane & 15;
  f32x4 acc[4][4] = {};
  for (int kt = 0; kt < K; kt += 32) {
    #pragma unroll
    for (int i = 0; i < 2; ++i) {
      int e = i * 256 + tid;
      int r = e >> 2, kk = (tid & 3) * 8;
      gll16(Ab  + (size_t)r * K + kt + kk, (char*)As + i * 4096 + w * 1024);
      gll16(Btb + (size_t)r * K + kt + kk, (char*)Bs + i * 4096 + w * 1024);
    }
    __syncthreads();
    f16x8 af[4], bf[4];
    #pragma unroll
    for (int m = 0; m < 4; ++m)
      af[m] = *(const f16x8*)&As[(wr * 64 + m * 16 + tt) * 32 + g * 8];
    #pragma unroll
    for (int n = 0; n < 4; ++n)
      bf[n] = *(const f16x8*)&Bs[(wc * 64 + n * 16 + tt) * 32 + g * 8];
    #pragma unroll
    for (int n = 0; n < 4; ++n)
      #pragma unroll
      for (int m = 0; m < 4; ++m)
        acc[m][n] = __builtin_amdgcn_mfma_f32_16x16x32_f16(af[m], bf[n], acc[m][n], 0, 0, 0);
    __syncthreads();
  }
  const size_t Cb = (size_t)b * sC;
  #pragma unroll
  for (int m = 0; m < 4; ++m)
    #pragma unroll
    for (int j = 0; j < 4; ++j) {
      int r = tm * 128 + wr * 64 + m * 16 + g * 4 + j;
      #pragma unroll
      for (int n = 0; n < 4; ++n) {
        int c = tn * 128 + wc * 64 + n * 16 + tt;
        size_t idx = Cb + (size_t)r * N + c;
        float v = acc[m][n][j];
        if (RESID) v += resid[idx];
        C[idx] = (CT)v;
      }
    }
}

// ---------------- K3: row softmax, IN-PLACE on f16 S ----------------
__global__ __launch_bounds__(256) void softmax_rows(f16* __restrict__ SP)
{
  __shared__ float sred[4];
  const size_t row = blockIdx.x;
  f16x8* Pr = (f16x8*)(SP + row * 2048);
  const int tid = threadIdx.x, w = tid >> 6, lane = tid & 63;
  f16x8 v = Pr[tid];
  float f[8];
  #pragma unroll
  for (int j = 0; j < 8; ++j) f[j] = (float)v[j];
  float mx = f[0];
  #pragma unroll
  for (int j = 1; j < 8; ++j) mx = fmaxf(mx, f[j]);
  #pragma unroll
  for (int mk = 1; mk < 64; mk <<= 1) mx = fmaxf(mx, __shfl_xor(mx, mk));
  if (lane == 0) sred[w] = mx;
  __syncthreads();
  mx = fmaxf(fmaxf(sred[0], sred[1]), fmaxf(sred[2], sred[3]));
  __syncthreads();
  float e[8], s = 0.f;
  #pragma unroll
  for (int j = 0; j < 8; ++j) { e[j] = __expf(f[j] - mx); s += e[j]; }
  #pragma unroll
  for (int mk = 1; mk < 64; mk <<= 1) s += __shfl_xor(s, mk);
  if (lane == 0) sred[w] = s;
  __syncthreads();
  s = sred[0] + sred[1] + sred[2] + sred[3];
  float inv = 1.f / s;
  f16x8 p;
  #pragma unroll
  for (int j = 0; j < 8; ++j) p[j] = (f16)(e[j] * inv);
  Pr[tid] = p;
}

// ---------------- host launcher ----------------
extern "C" void kernel_launch(void* const* d_in, const int* in_sizes, int n_in,
                              void* d_out, int out_size, void* d_ws, size_t ws_size,
                              hipStream_t stream) {
  const float* qs   = (const float*)d_in[0];   // [8,2048,512]
  const float* kv   = (const float*)d_in[1];   // [8,2048,768]
  const float* Wq   = (const float*)d_in[2];
  const float* bq   = (const float*)d_in[3];
  const float* gq   = (const float*)d_in[4];
  const float* beq  = (const float*)d_in[5];
  const float* Wk   = (const float*)d_in[6];
  const float* bk   = (const float*)d_in[7];
  const float* gk   = (const float*)d_in[8];
  const float* bek  = (const float*)d_in[9];
  const float* Wv   = (const float*)d_in[10];
  const float* bv   = (const float*)d_in[11];
  const float* gv   = (const float*)d_in[12];
  const float* bev  = (const float*)d_in[13];
  float* out = (float*)d_out;

  // ---- workspace layout (peak 119,537,664 B ~= 114 MB) ----
  // phase 1 (casts + proj_ln): q16,k16,vt,weights,qs16,kv16  -> 94,371,840 B
  // phase 2 (attn): S/P (f16) OVERLAPS qs16/kv16 (dead after proj_ln)
  char* ws = (char*)d_ws;
  f16* q16  = (f16*)(ws + 0);            // 16,777,216 B  [8,2048,512]
  f16* k16  = (f16*)(ws + 16777216);     // 16,777,216 B  [8,2048,512]
  f16* vt   = (f16*)(ws + 33554432);     // 16,777,216 B  [8,512,2048]
  f16* Wqt  = (f16*)(ws + 50331648);     //    524,288 B  [512][512]
  f16* Wkt  = (f16*)(ws + 50855936);     //    786,432 B  [512][768]
  f16* Wvt  = (f16*)(ws + 51642368);     //    786,432 B  [512][768]
  f16* qs16 = (f16*)(ws + 52428800);     // 16,777,216 B
  f16* kv16 = (f16*)(ws + 69206016);     // 25,165,824 B  (ends 94,371,840)
  f16* S    = (f16*)(ws + 52428800);     // 67,108,864 B  [8,2048,2048] f16
                                         // (ends 119,537,664; overlaps qs16/kv16)

  // K0: casts
  cast_f2h<<<8192, 256, 0, stream>>>(qs, qs16, 2097152);
  cast_f2h<<<12288, 256, 0, stream>>>(kv, kv16, 3145728);
  cast_transpose<<<1024, 256, 0, stream>>>(Wq, Wqt, 512, 512);
  cast_transpose<<<1536, 256, 0, stream>>>(Wk, Wkt, 768, 512);
  cast_transpose<<<1536, 256, 0, stream>>>(Wv, Wvt, 768, 512);

  // K1: fused projections + LN (768 blocks = 3 projections x 256 tiles)
  proj_ln<<<768, 512, 0, stream>>>(qs16, kv16, Wqt, Wkt, Wvt,
                                   bq, gq, beq, bk, gk, bek, bv, gv, bev,
                                   q16, k16, vt);

  // K2: S[b,l,L] = sum_c k[b,l,c] * q[b,L,c]   (NT, f16 out)
  gemm_nt<false, f16><<<2048, 256, 0, stream>>>(
      k16, q16, S, nullptr,
      /*K=*/512, /*tilesM=*/16, /*tilesN=*/16, /*N=*/2048,
      (size_t)2048 * 512, (size_t)2048 * 512, (size_t)2048 * 2048);

  // K3: row softmax over L, in-place f16
  softmax_rows<<<16384, 256, 0, stream>>>(S);

  // K4: out[b,l,c] = sum_L P[b,l,L] * vt[b,c,L] + qs[b,l,c]
  gemm_nt<true, float><<<512, 256, 0, stream>>>(
      S, vt, out, qs,
      /*K=*/2048, /*tilesM=*/16, /*tilesN=*/4, /*N=*/512,
      (size_t)2048 * 2048, (size_t)512 * 2048, (size_t)2048 * 512);
}

// Round 3
// 356.526 us; speedup vs baseline: 1.0903x; 1.0903x over previous
//
#include <hip/hip_runtime.h>

typedef _Float16 f16;
typedef _Float16 f16x4 __attribute__((ext_vector_type(4)));
typedef _Float16 f16x8 __attribute__((ext_vector_type(8)));
typedef float f32x4 __attribute__((ext_vector_type(4)));
typedef unsigned int u32;

// Problem dims (fixed by setup_inputs)
#define NB   8
#define SEQ  2048
#define DQ_  512
#define DKV_ 768
#define HD_  512

__device__ __forceinline__ void gll16(const void* g, void* l) {
  __builtin_amdgcn_global_load_lds(
      (const __attribute__((address_space(1))) u32*)g,
      (__attribute__((address_space(3))) u32*)l, 16, 0, 0);
}

// ---------------- K0b: transposing f32 -> f16 cast for weights ----------------
// in: [K][N] f32, out: [N][K] f16
__global__ __launch_bounds__(256) void cast_transpose(const float* __restrict__ in,
                                                      f16* __restrict__ out,
                                                      int K, int N) {
  int i = blockIdx.x * 256 + threadIdx.x;
  if (i >= K * N) return;
  int n = i / K, k = i % K;
  out[i] = (f16)in[k * N + n];
}

// ---------------- K1: fused GEMM + LayerNorm ----------------
// Block: 512 thr (8 waves). Tile: 64 rows x 512 cols (full row -> in-block LN).
// Wave w owns cols [64w, 64w+64). BK=32, mfma 16x16x32 f16, f32 accum.
// X read DIRECTLY from f32 input (reg-staged, converted, ds_write into padded
// stride-40 tile -> conflict-free). W staged via gll16 with chunk-XOR swizzle
// (rule 21: linear LDS dest + inverse-swizzled global source + swizzled read).
// proj 2 (v) writes output TRANSPOSED per batch: vt[b][c][l].
__global__ __launch_bounds__(512) void proj_ln(
    const float* __restrict__ xq, const float* __restrict__ xkv,
    const f16* __restrict__ wqt, const f16* __restrict__ wkt, const f16* __restrict__ wvt,
    const float* __restrict__ bq, const float* __restrict__ gq, const float* __restrict__ beq,
    const float* __restrict__ bk, const float* __restrict__ gk, const float* __restrict__ bek,
    const float* __restrict__ bv, const float* __restrict__ gv, const float* __restrict__ bev,
    f16* __restrict__ outq, f16* __restrict__ outk, f16* __restrict__ outvt)
{
  // LDS: Xs [64][40] f16 = 5120 B (padded, reg-staged), Wts [512][32] = 32768 B.
  // Epilogue reuses [0,36864) as trans [256][72]. red/mus/rss after 37888.
  __shared__ char smem[37888 + 4096 + 512];
  f16* Xs    = (f16*)smem;                    // [64][40]
  f16* Wts   = (f16*)(smem + 5120);           // [512][32]
  f16* trans = (f16*)smem;                    // [256][72]  (epilogue reuse)
  float* red = (float*)(smem + 37888);        // [64][8][2]
  float* mus = (float*)(smem + 37888 + 4096); // [64]
  float* rss = mus + 64;                      // [64]

  const int proj = blockIdx.x >> 8;
  const int tile = blockIdx.x & 255;
  const float* X; const f16* Wt; const float *bias, *gam, *bet; f16* out; int KD;
  if (proj == 0)      { X = xq;  Wt = wqt; bias = bq; gam = gq; bet = beq; out = outq;  KD = 512; }
  else if (proj == 1) { X = xkv; Wt = wkt; bias = bk; gam = gk; bet = bek; out = outk;  KD = 768; }
  else                { X = xkv; Wt = wvt; bias = bv; gam = gv; bet = bev; out = outvt; KD = 768; }

  const int row0 = tile * 64;
  const int tid = threadIdx.x;
  const int w = tid >> 6;
  const int lane = tid & 63;
  const int g = lane >> 4, tt = lane & 15;

  f32x4 acc[4][4] = {};

  const int nk = KD >> 5;
  for (int kt = 0; kt < nk; ++kt) {
    const int k0 = kt * 32;
    if (tid < 256) {                       // reg-stage X tile [64][32] from f32
      int r = tid >> 2, c = tid & 3;
      const float* src = X + (size_t)(row0 + r) * KD + k0 + c * 8;
      float4 a = *(const float4*)src;
      float4 b = *(const float4*)(src + 4);
      f16x8 h;
      h[0] = (f16)a.x; h[1] = (f16)a.y; h[2] = (f16)a.z; h[3] = (f16)a.w;
      h[4] = (f16)b.x; h[5] = (f16)b.y; h[6] = (f16)b.z; h[7] = (f16)b.w;
      *(f16x8*)&Xs[r * 40 + c * 8] = h;
    }
    #pragma unroll
    for (int i = 0; i < 4; ++i) {          // stage Wt tile [512][32], swizzled source
      int o = i * 8192 + tid * 16;         // linear LDS byte offset
      int r = o >> 6;                      // 64B rows
      int c = (o >> 4) & 3;                // 16B chunk within row
      int cs = c ^ (r & 3);                // inverse swizzle on SOURCE
      gll16(Wt + (size_t)r * KD + k0 + cs * 8, (char*)Wts + o);
    }
    __syncthreads();
    f16x8 af[4];
    #pragma unroll
    for (int m = 0; m < 4; ++m)
      af[m] = *(const f16x8*)&Xs[(m * 16 + tt) * 40 + g * 8];
    #pragma unroll
    for (int n = 0; n < 4; ++n) {
      int R = w * 64 + n * 16 + tt;
      int ch = g ^ (R & 3);                // swizzled read
      f16x8 bf = *(const f16x8*)&Wts[R * 32 + ch * 8];
      #pragma unroll
      for (int m = 0; m < 4; ++m)
        acc[m][n] = __builtin_amdgcn_mfma_f32_16x16x32_f16(af[m], bf, acc[m][n], 0, 0, 0);
    }
    __syncthreads();
  }

  // ---- epilogue: bias add + LayerNorm stats (f32) ----
  float bias4[4], gam4[4], bet4[4];
  #pragma unroll
  for (int n = 0; n < 4; ++n) {
    int c = w * 64 + n * 16 + tt;
    bias4[n] = bias[c]; gam4[n] = gam[c]; bet4[n] = bet[c];
  }
  float rsum[4][4], rsq[4][4];
  #pragma unroll
  for (int m = 0; m < 4; ++m)
    #pragma unroll
    for (int j = 0; j < 4; ++j) { rsum[m][j] = 0.f; rsq[m][j] = 0.f; }
  #pragma unroll
  for (int m = 0; m < 4; ++m)
    #pragma unroll
    for (int n = 0; n < 4; ++n)
      #pragma unroll
      for (int j = 0; j < 4; ++j) {
        float h = acc[m][n][j] + bias4[n];
        acc[m][n][j] = h;
        rsum[m][j] += h; rsq[m][j] += h * h;
      }
  // reduce across the 16 lanes sharing each row (lane bits 0..3)
  #pragma unroll
  for (int mk = 1; mk < 16; mk <<= 1)
    #pragma unroll
    for (int m = 0; m < 4; ++m)
      #pragma unroll
      for (int j = 0; j < 4; ++j) {
        rsum[m][j] += __shfl_xor(rsum[m][j], mk);
        rsq[m][j]  += __shfl_xor(rsq[m][j], mk);
      }
  if (tt == 0) {
    #pragma unroll
    for (int m = 0; m < 4; ++m)
      #pragma unroll
      for (int j = 0; j < 4; ++j) {
        int r = m * 16 + g * 4 + j;
        red[(r * 8 + w) * 2 + 0] = rsum[m][j];
        red[(r * 8 + w) * 2 + 1] = rsq[m][j];
      }
  }
  __syncthreads();
  if (tid < 64) {   // cross-wave combine: one thread per row
    float s = 0.f, sq = 0.f;
    #pragma unroll
    for (int w2 = 0; w2 < 8; ++w2) {
      s  += red[(tid * 8 + w2) * 2 + 0];
      sq += red[(tid * 8 + w2) * 2 + 1];
    }
    float mu = s * (1.f / 512.f);
    float var = sq * (1.f / 512.f) - mu * mu;
    mus[tid] = mu;
    rss[tid] = rsqrtf(var + 1e-5f);
  }
  __syncthreads();
  #pragma unroll
  for (int m = 0; m < 4; ++m)
    #pragma unroll
    for (int j = 0; j < 4; ++j) {
      int r = m * 16 + g * 4 + j;
      float mu = mus[r], rs = rss[r];
      #pragma unroll
      for (int n = 0; n < 4; ++n)
        acc[m][n][j] = (acc[m][n][j] - mu) * rs * gam4[n] + bet4[n];
    }

  if (proj != 2) {
    // straight f16 store: out[row][col]
    #pragma unroll
    for (int m = 0; m < 4; ++m)
      #pragma unroll
      for (int j = 0; j < 4; ++j) {
        int r = row0 + m * 16 + g * 4 + j;
        #pragma unroll
        for (int n = 0; n < 4; ++n)
          out[(size_t)r * 512 + w * 64 + n * 16 + tt] = (f16)acc[m][n][j];
      }
  } else {
    // transposed store via LDS: vt[b][c][l], two 256-col chunks
    const int bch = row0 >> 11, l0 = row0 & 2047;
    __syncthreads();
    for (int half = 0; half < 2; ++half) {
      if ((w >> 2) == half) {
        #pragma unroll
        for (int m = 0; m < 4; ++m)
          #pragma unroll
          for (int n = 0; n < 4; ++n)
            #pragma unroll
            for (int j = 0; j < 4; ++j)
              trans[((w & 3) * 64 + n * 16 + tt) * 72 + (m * 16 + g * 4 + j)] =
                  (f16)acc[m][n][j];
      }
      __syncthreads();
      {
        int c = tid >> 1, ii = tid & 1;
        size_t gb = (size_t)bch * (512 * 2048) + (size_t)(half * 256 + c) * 2048
                    + l0 + ii * 32;
        #pragma unroll
        for (int q2 = 0; q2 < 4; ++q2)
          *(f16x8*)&out[gb + q2 * 8] = *(const f16x8*)&trans[c * 72 + ii * 32 + q2 * 8];
      }
      __syncthreads();
    }
  }
}

// ---------------- K2/K4: batched NT GEMM, BK=64, chunk-swizzled LDS ----------
// C[b][m][n] = sum_k A[b][m][k] * Bt[b][n][k]  (+ resid), lda = ldb = K.
// 128x128 tile, BK=64, 4 waves in 2x2, mfma 16x16x32 f16.
// LDS rows are 128B (8 chunks of 16B). Swizzle: physical chunk c holds logical
// chunk c^(row&7); gll16 dest stays linear, global source col pre-swizzled,
// fragment reads apply the same XOR -> conflict-free ds_read_b128.
template <bool RESID, typename CT>
__global__ __launch_bounds__(256) void gemm_nt(
    const f16* __restrict__ A, const f16* __restrict__ Bt,
    CT* __restrict__ C, const float* __restrict__ resid,
    int K, int tilesM, int tilesN, int N,
    size_t sA, size_t sB, size_t sC)
{
  __shared__ f16 As[128 * 64];
  __shared__ f16 Bs[128 * 64];
  const int bpb = tilesM * tilesN;
  const int b = blockIdx.x / bpb;
  const int t = blockIdx.x % bpb;
  const int tm = t % tilesM, tn = t / tilesM;
  const f16* Ab  = A  + (size_t)b * sA + (size_t)tm * 128 * K;
  const f16* Btb = Bt + (size_t)b * sB + (size_t)tn * 128 * K;
  const int tid = threadIdx.x, w = tid >> 6, lane = tid & 63;
  const int wr = w >> 1, wc = w & 1;
  const int g = lane >> 4, tt = lane & 15;
  f32x4 acc[4][4] = {};
  for (int kt = 0; kt < K; kt += 64) {
    #pragma unroll
    for (int i = 0; i < 4; ++i) {
      int o = i * 4096 + tid * 16;         // linear LDS byte offset
      int r = o >> 7;                      // 128B rows
      int c = (o >> 4) & 7;                // 16B chunk
      int cs = c ^ (r & 7);                // inverse swizzle on SOURCE
      gll16(Ab  + (size_t)r * K + kt + cs * 8, (char*)As + o);
      gll16(Btb + (size_t)r * K + kt + cs * 8, (char*)Bs + o);
    }
    __syncthreads();
    #pragma unroll
    for (int kk = 0; kk < 2; ++kk) {
      f16x8 af[4], bf[4];
      #pragma unroll
      for (int m = 0; m < 4; ++m) {
        int R = wr * 64 + m * 16 + tt;
        int ch = (kk * 4 + g) ^ (R & 7);
        af[m] = *(const f16x8*)&As[R * 64 + ch * 8];
      }
      #pragma unroll
      for (int n = 0; n < 4; ++n) {
        int R = wc * 64 + n * 16 + tt;
        int ch = (kk * 4 + g) ^ (R & 7);
        bf[n] = *(const f16x8*)&Bs[R * 64 + ch * 8];
      }
      #pragma unroll
      for (int n = 0; n < 4; ++n)
        #pragma unroll
        for (int m = 0; m < 4; ++m)
          acc[m][n] = __builtin_amdgcn_mfma_f32_16x16x32_f16(af[m], bf[n], acc[m][n], 0, 0, 0);
    }
    __syncthreads();
  }
  const size_t Cb = (size_t)b * sC;
  #pragma unroll
  for (int m = 0; m < 4; ++m)
    #pragma unroll
    for (int j = 0; j < 4; ++j) {
      int r = tm * 128 + wr * 64 + m * 16 + g * 4 + j;
      #pragma unroll
      for (int n = 0; n < 4; ++n) {
        int c = tn * 128 + wc * 64 + n * 16 + tt;
        size_t idx = Cb + (size_t)r * N + c;
        float v = acc[m][n][j];
        if (RESID) v += resid[idx];
        C[idx] = (CT)v;
      }
    }
}

// ---------------- K3: row softmax, IN-PLACE on f16 S ----------------
__global__ __launch_bounds__(256) void softmax_rows(f16* __restrict__ SP)
{
  __shared__ float sred[4];
  const size_t row = blockIdx.x;
  f16x8* Pr = (f16x8*)(SP + row * 2048);
  const int tid = threadIdx.x, w = tid >> 6, lane = tid & 63;
  f16x8 v = Pr[tid];
  float f[8];
  #pragma unroll
  for (int j = 0; j < 8; ++j) f[j] = (float)v[j];
  float mx = f[0];
  #pragma unroll
  for (int j = 1; j < 8; ++j) mx = fmaxf(mx, f[j]);
  #pragma unroll
  for (int mk = 1; mk < 64; mk <<= 1) mx = fmaxf(mx, __shfl_xor(mx, mk));
  if (lane == 0) sred[w] = mx;
  __syncthreads();
  mx = fmaxf(fmaxf(sred[0], sred[1]), fmaxf(sred[2], sred[3]));
  __syncthreads();
  float e[8], s = 0.f;
  #pragma unroll
  for (int j = 0; j < 8; ++j) { e[j] = __expf(f[j] - mx); s += e[j]; }
  #pragma unroll
  for (int mk = 1; mk < 64; mk <<= 1) s += __shfl_xor(s, mk);
  if (lane == 0) sred[w] = s;
  __syncthreads();
  s = sred[0] + sred[1] + sred[2] + sred[3];
  float inv = 1.f / s;
  f16x8 p;
  #pragma unroll
  for (int j = 0; j < 8; ++j) p[j] = (f16)(e[j] * inv);
  Pr[tid] = p;
}

// ---------------- host launcher ----------------
extern "C" void kernel_launch(void* const* d_in, const int* in_sizes, int n_in,
                              void* d_out, int out_size, void* d_ws, size_t ws_size,
                              hipStream_t stream) {
  const float* qs   = (const float*)d_in[0];   // [8,2048,512]
  const float* kv   = (const float*)d_in[1];   // [8,2048,768]
  const float* Wq   = (const float*)d_in[2];
  const float* bq   = (const float*)d_in[3];
  const float* gq   = (const float*)d_in[4];
  const float* beq  = (const float*)d_in[5];
  const float* Wk   = (const float*)d_in[6];
  const float* bk   = (const float*)d_in[7];
  const float* gk   = (const float*)d_in[8];
  const float* bek  = (const float*)d_in[9];
  const float* Wv   = (const float*)d_in[10];
  const float* bv   = (const float*)d_in[11];
  const float* gv   = (const float*)d_in[12];
  const float* bev  = (const float*)d_in[13];
  float* out = (float*)d_out;

  // ---- workspace layout (peak 117,440,512 B ~= 112 MB) ----
  char* ws = (char*)d_ws;
  f16* q16  = (f16*)(ws + 0);            // 16,777,216 B  [8,2048,512]
  f16* k16  = (f16*)(ws + 16777216);     // 16,777,216 B  [8,2048,512]
  f16* vt   = (f16*)(ws + 33554432);     // 16,777,216 B  [8,512,2048]
  f16* Wqt  = (f16*)(ws + 50331648);     //    524,288 B  [512][512]
  f16* Wkt  = (f16*)(ws + 50855936);     //    786,432 B  [512][768]
  f16* Wvt  = (f16*)(ws + 51642368);     //    786,432 B  [512][768]
  f16* S    = (f16*)(ws + 52428800);     // 67,108,864 B  [8,2048,2048] f16
                                         // ends 119,537,664 B

  // K0: weight transpose+cast (small)
  cast_transpose<<<1024, 256, 0, stream>>>(Wq, Wqt, 512, 512);
  cast_transpose<<<1536, 256, 0, stream>>>(Wk, Wkt, 768, 512);
  cast_transpose<<<1536, 256, 0, stream>>>(Wv, Wvt, 768, 512);

  // K1: fused projections + LN (768 blocks = 3 projections x 256 tiles)
  proj_ln<<<768, 512, 0, stream>>>(qs, kv, Wqt, Wkt, Wvt,
                                   bq, gq, beq, bk, gk, bek, bv, gv, bev,
                                   q16, k16, vt);

  // K2: S[b,l,L] = sum_c k[b,l,c] * q[b,L,c]   (NT, f16 out)
  gemm_nt<false, f16><<<2048, 256, 0, stream>>>(
      k16, q16, S, nullptr,
      /*K=*/512, /*tilesM=*/16, /*tilesN=*/16, /*N=*/2048,
      (size_t)2048 * 512, (size_t)2048 * 512, (size_t)2048 * 2048);

  // K3: row softmax over L, in-place f16
  softmax_rows<<<16384, 256, 0, stream>>>(S);

  // K4: out[b,l,c] = sum_L P[b,l,L] * vt[b,c,L] + qs[b,l,c]
  gemm_nt<true, float><<<512, 256, 0, stream>>>(
      S, vt, out, qs,
      /*K=*/2048, /*tilesM=*/16, /*tilesN=*/4, /*N=*/512,
      (size_t)2048 * 2048, (size_t)512 * 2048, (size_t)2048 * 512);
}

// Round 4
// 354.261 us; speedup vs baseline: 1.0972x; 1.0064x over previous
//
#include <hip/hip_runtime.h>

typedef _Float16 f16;
typedef _Float16 f16x4 __attribute__((ext_vector_type(4)));
typedef _Float16 f16x8 __attribute__((ext_vector_type(8)));
typedef float f32x4 __attribute__((ext_vector_type(4)));
typedef unsigned int u32;

// Problem dims (fixed by setup_inputs)
#define NB   8
#define SEQ  2048
#define DQ_  512
#define DKV_ 768
#define HD_  512

__device__ __forceinline__ void gll16(const void* g, void* l) {
  __builtin_amdgcn_global_load_lds(
      (const __attribute__((address_space(1))) u32*)g,
      (__attribute__((address_space(3))) u32*)l, 16, 0, 0);
}

// ---------------- K0b: transposing f32 -> f16 cast for weights ----------------
// in: [K][N] f32, out: [N][K] f16
__global__ __launch_bounds__(256) void cast_transpose(const float* __restrict__ in,
                                                      f16* __restrict__ out,
                                                      int K, int N) {
  int i = blockIdx.x * 256 + threadIdx.x;
  if (i >= K * N) return;
  int n = i / K, k = i % K;
  out[i] = (f16)in[k * N + n];
}

// ---------------- K1: fused GEMM + LayerNorm ----------------
// Block: 512 thr (8 waves). Tile: 64 rows x 512 cols (full row -> in-block LN).
// Wave w owns cols [64w, 64w+64). mfma 16x16x32 f16, f32 accum.
// NEW STRUCTURE (r4): W fragments load DIRECTLY from global (L2-resident,
// no LDS staging, no barrier gating -> compiler pipelines via vmcnt).
// X staged in 128-wide K-strips: [64][128] f16, stride 136 (reg-staged from
// f32 with conversion). Barriers only at strip boundaries (4-6 per block).
// proj 2 (v) writes output TRANSPOSED per batch: vt[b][c][l].
__global__ __launch_bounds__(512) void proj_ln(
    const float* __restrict__ xq, const float* __restrict__ xkv,
    const f16* __restrict__ wqt, const f16* __restrict__ wkt, const f16* __restrict__ wvt,
    const float* __restrict__ bq, const float* __restrict__ gq, const float* __restrict__ beq,
    const float* __restrict__ bk, const float* __restrict__ gk, const float* __restrict__ bek,
    const float* __restrict__ bv, const float* __restrict__ gv, const float* __restrict__ bev,
    f16* __restrict__ outq, f16* __restrict__ outk, f16* __restrict__ outvt)
{
  // LDS: Xs [64][136] f16 = 17408 B; epilogue reuses [0,36864) as trans
  // [256][72]. red/mus/rss after 36864.
  __shared__ char smem[36864 + 4096 + 512];
  f16* Xs    = (f16*)smem;                    // [64][136]
  f16* trans = (f16*)smem;                    // [256][72]  (epilogue reuse)
  float* red = (float*)(smem + 36864);        // [64][8][2]
  float* mus = (float*)(smem + 36864 + 4096); // [64]
  float* rss = mus + 64;                      // [64]

  const int proj = blockIdx.x >> 8;
  const int tile = blockIdx.x & 255;
  const float* X; const f16* Wt; const float *bias, *gam, *bet; f16* out; int KD;
  if (proj == 0)      { X = xq;  Wt = wqt; bias = bq; gam = gq; bet = beq; out = outq;  KD = 512; }
  else if (proj == 1) { X = xkv; Wt = wkt; bias = bk; gam = gk; bet = bek; out = outk;  KD = 768; }
  else                { X = xkv; Wt = wvt; bias = bv; gam = gv; bet = bev; out = outvt; KD = 768; }

  const int row0 = tile * 64;
  const int tid = threadIdx.x;
  const int w = tid >> 6;
  const int lane = tid & 63;
  const int g = lane >> 4, tt = lane & 15;

  // Hoisted row-base pointers (KD runtime -> avoid per-load mul)
  const float* xrow = X + (size_t)(row0 + (tid >> 3)) * KD + (tid & 7) * 16;
  const f16* wrow[4];
  #pragma unroll
  for (int n = 0; n < 4; ++n)
    wrow[n] = Wt + (size_t)(w * 64 + n * 16 + tt) * KD + g * 8;

  f32x4 acc[4][4] = {};

  const int nstrip = KD >> 7;                 // 4 (q) or 6 (kv)
  for (int st = 0; st < nstrip; ++st) {
    const int ks = st * 128;
    {  // stage X strip [64][128] f32->f16, all 512 threads, 16 f32 each
      const int r = tid >> 3, c0 = (tid & 7) * 16;
      const float* src = xrow + ks;
      float4 a = *(const float4*)(src);
      float4 b = *(const float4*)(src + 4);
      float4 c = *(const float4*)(src + 8);
      float4 d = *(const float4*)(src + 12);
      f16x8 h0, h1;
      h0[0] = (f16)a.x; h0[1] = (f16)a.y; h0[2] = (f16)a.z; h0[3] = (f16)a.w;
      h0[4] = (f16)b.x; h0[5] = (f16)b.y; h0[6] = (f16)b.z; h0[7] = (f16)b.w;
      h1[0] = (f16)c.x; h1[1] = (f16)c.y; h1[2] = (f16)c.z; h1[3] = (f16)c.w;
      h1[4] = (f16)d.x; h1[5] = (f16)d.y; h1[6] = (f16)d.z; h1[7] = (f16)d.w;
      *(f16x8*)&Xs[r * 136 + c0]     = h0;
      *(f16x8*)&Xs[r * 136 + c0 + 8] = h1;
    }
    __syncthreads();
    #pragma unroll
    for (int s = 0; s < 4; ++s) {
      f16x8 af[4], bf[4];
      #pragma unroll
      for (int n = 0; n < 4; ++n)
        bf[n] = *(const f16x8*)(wrow[n] + ks + s * 32);
      #pragma unroll
      for (int m = 0; m < 4; ++m)
        af[m] = *(const f16x8*)&Xs[(m * 16 + tt) * 136 + s * 32 + g * 8];
      #pragma unroll
      for (int n = 0; n < 4; ++n)
        #pragma unroll
        for (int m = 0; m < 4; ++m)
          acc[m][n] = __builtin_amdgcn_mfma_f32_16x16x32_f16(af[m], bf[n], acc[m][n], 0, 0, 0);
    }
    __syncthreads();
  }

  // ---- epilogue: bias add + LayerNorm stats (f32) ----
  float bias4[4], gam4[4], bet4[4];
  #pragma unroll
  for (int n = 0; n < 4; ++n) {
    int c = w * 64 + n * 16 + tt;
    bias4[n] = bias[c]; gam4[n] = gam[c]; bet4[n] = bet[c];
  }
  float rsum[4][4], rsq[4][4];
  #pragma unroll
  for (int m = 0; m < 4; ++m)
    #pragma unroll
    for (int j = 0; j < 4; ++j) { rsum[m][j] = 0.f; rsq[m][j] = 0.f; }
  #pragma unroll
  for (int m = 0; m < 4; ++m)
    #pragma unroll
    for (int n = 0; n < 4; ++n)
      #pragma unroll
      for (int j = 0; j < 4; ++j) {
        float h = acc[m][n][j] + bias4[n];
        acc[m][n][j] = h;
        rsum[m][j] += h; rsq[m][j] += h * h;
      }
  // reduce across the 16 lanes sharing each row (lane bits 0..3)
  #pragma unroll
  for (int mk = 1; mk < 16; mk <<= 1)
    #pragma unroll
    for (int m = 0; m < 4; ++m)
      #pragma unroll
      for (int j = 0; j < 4; ++j) {
        rsum[m][j] += __shfl_xor(rsum[m][j], mk);
        rsq[m][j]  += __shfl_xor(rsq[m][j], mk);
      }
  if (tt == 0) {
    #pragma unroll
    for (int m = 0; m < 4; ++m)
      #pragma unroll
      for (int j = 0; j < 4; ++j) {
        int r = m * 16 + g * 4 + j;
        red[(r * 8 + w) * 2 + 0] = rsum[m][j];
        red[(r * 8 + w) * 2 + 1] = rsq[m][j];
      }
  }
  __syncthreads();
  if (tid < 64) {   // cross-wave combine: one thread per row
    float s = 0.f, sq = 0.f;
    #pragma unroll
    for (int w2 = 0; w2 < 8; ++w2) {
      s  += red[(tid * 8 + w2) * 2 + 0];
      sq += red[(tid * 8 + w2) * 2 + 1];
    }
    float mu = s * (1.f / 512.f);
    float var = sq * (1.f / 512.f) - mu * mu;
    mus[tid] = mu;
    rss[tid] = rsqrtf(var + 1e-5f);
  }
  __syncthreads();
  #pragma unroll
  for (int m = 0; m < 4; ++m)
    #pragma unroll
    for (int j = 0; j < 4; ++j) {
      int r = m * 16 + g * 4 + j;
      float mu = mus[r], rs = rss[r];
      #pragma unroll
      for (int n = 0; n < 4; ++n)
        acc[m][n][j] = (acc[m][n][j] - mu) * rs * gam4[n] + bet4[n];
    }

  if (proj != 2) {
    // straight f16 store: out[row][col]
    #pragma unroll
    for (int m = 0; m < 4; ++m)
      #pragma unroll
      for (int j = 0; j < 4; ++j) {
        int r = row0 + m * 16 + g * 4 + j;
        #pragma unroll
        for (int n = 0; n < 4; ++n)
          out[(size_t)r * 512 + w * 64 + n * 16 + tt] = (f16)acc[m][n][j];
      }
  } else {
    // transposed store via LDS: vt[b][c][l], two 256-col chunks
    const int bch = row0 >> 11, l0 = row0 & 2047;
    __syncthreads();
    for (int half = 0; half < 2; ++half) {
      if ((w >> 2) == half) {
        #pragma unroll
        for (int m = 0; m < 4; ++m)
          #pragma unroll
          for (int n = 0; n < 4; ++n)
            #pragma unroll
            for (int j = 0; j < 4; ++j)
              trans[((w & 3) * 64 + n * 16 + tt) * 72 + (m * 16 + g * 4 + j)] =
                  (f16)acc[m][n][j];
      }
      __syncthreads();
      {
        int c = tid >> 1, ii = tid & 1;
        size_t gb = (size_t)bch * (512 * 2048) + (size_t)(half * 256 + c) * 2048
                    + l0 + ii * 32;
        #pragma unroll
        for (int q2 = 0; q2 < 4; ++q2)
          *(f16x8*)&out[gb + q2 * 8] = *(const f16x8*)&trans[c * 72 + ii * 32 + q2 * 8];
      }
      __syncthreads();
    }
  }
}

// ---------------- K2/K4: batched NT GEMM, BK=64, chunk-swizzled LDS ----------
// C[b][m][n] = sum_k A[b][m][k] * Bt[b][n][k]  (+ resid), lda = ldb = K.
// 128x128 tile, BK=64, 4 waves in 2x2, mfma 16x16x32 f16.
// T1: bijective XCD swizzle (grid % 8 == 0 for all call sites).
template <bool RESID, typename CT>
__global__ __launch_bounds__(256) void gemm_nt(
    const f16* __restrict__ A, const f16* __restrict__ Bt,
    CT* __restrict__ C, const float* __restrict__ resid,
    int K, int tilesM, int tilesN, int N,
    size_t sA, size_t sB, size_t sC)
{
  __shared__ f16 As[128 * 64];
  __shared__ f16 Bs[128 * 64];
  // T1 XCD swizzle: hw block `orig` executes logical tile `bid` such that
  // each XCD (orig%8) gets a CONTIGUOUS logical range -> L2 panel reuse.
  const int nwg = gridDim.x;
  const int orig = blockIdx.x;
  const int bid = (orig & 7) * (nwg >> 3) + (orig >> 3);
  const int bpb = tilesM * tilesN;
  const int b = bid / bpb;
  const int t = bid % bpb;
  const int tm = t % tilesM, tn = t / tilesM;
  const f16* Ab  = A  + (size_t)b * sA + (size_t)tm * 128 * K;
  const f16* Btb = Bt + (size_t)b * sB + (size_t)tn * 128 * K;
  const int tid = threadIdx.x, w = tid >> 6, lane = tid & 63;
  const int wr = w >> 1, wc = w & 1;
  const int g = lane >> 4, tt = lane & 15;
  f32x4 acc[4][4] = {};
  for (int kt = 0; kt < K; kt += 64) {
    #pragma unroll
    for (int i = 0; i < 4; ++i) {
      int o = i * 4096 + tid * 16;         // linear LDS byte offset
      int r = o >> 7;                      // 128B rows
      int c = (o >> 4) & 7;                // 16B chunk
      int cs = c ^ (r & 7);                // inverse swizzle on SOURCE
      gll16(Ab  + (size_t)r * K + kt + cs * 8, (char*)As + o);
      gll16(Btb + (size_t)r * K + kt + cs * 8, (char*)Bs + o);
    }
    __syncthreads();
    #pragma unroll
    for (int kk = 0; kk < 2; ++kk) {
      f16x8 af[4], bf[4];
      #pragma unroll
      for (int m = 0; m < 4; ++m) {
        int R = wr * 64 + m * 16 + tt;
        int ch = (kk * 4 + g) ^ (R & 7);
        af[m] = *(const f16x8*)&As[R * 64 + ch * 8];
      }
      #pragma unroll
      for (int n = 0; n < 4; ++n) {
        int R = wc * 64 + n * 16 + tt;
        int ch = (kk * 4 + g) ^ (R & 7);
        bf[n] = *(const f16x8*)&Bs[R * 64 + ch * 8];
      }
      #pragma unroll
      for (int n = 0; n < 4; ++n)
        #pragma unroll
        for (int m = 0; m < 4; ++m)
          acc[m][n] = __builtin_amdgcn_mfma_f32_16x16x32_f16(af[m], bf[n], acc[m][n], 0, 0, 0);
    }
    __syncthreads();
  }
  const size_t Cb = (size_t)b * sC;
  #pragma unroll
  for (int m = 0; m < 4; ++m)
    #pragma unroll
    for (int j = 0; j < 4; ++j) {
      int r = tm * 128 + wr * 64 + m * 16 + g * 4 + j;
      #pragma unroll
      for (int n = 0; n < 4; ++n) {
        int c = tn * 128 + wc * 64 + n * 16 + tt;
        size_t idx = Cb + (size_t)r * N + c;
        float v = acc[m][n][j];
        if (RESID) v += resid[idx];
        C[idx] = (CT)v;
      }
    }
}

// ---------------- K3: row softmax, IN-PLACE on f16 S ----------------
__global__ __launch_bounds__(256) void softmax_rows(f16* __restrict__ SP)
{
  __shared__ float sred[4];
  const size_t row = blockIdx.x;
  f16x8* Pr = (f16x8*)(SP + row * 2048);
  const int tid = threadIdx.x, w = tid >> 6, lane = tid & 63;
  f16x8 v = Pr[tid];
  float f[8];
  #pragma unroll
  for (int j = 0; j < 8; ++j) f[j] = (float)v[j];
  float mx = f[0];
  #pragma unroll
  for (int j = 1; j < 8; ++j) mx = fmaxf(mx, f[j]);
  #pragma unroll
  for (int mk = 1; mk < 64; mk <<= 1) mx = fmaxf(mx, __shfl_xor(mx, mk));
  if (lane == 0) sred[w] = mx;
  __syncthreads();
  mx = fmaxf(fmaxf(sred[0], sred[1]), fmaxf(sred[2], sred[3]));
  __syncthreads();
  float e[8], s = 0.f;
  #pragma unroll
  for (int j = 0; j < 8; ++j) { e[j] = __expf(f[j] - mx); s += e[j]; }
  #pragma unroll
  for (int mk = 1; mk < 64; mk <<= 1) s += __shfl_xor(s, mk);
  if (lane == 0) sred[w] = s;
  __syncthreads();
  s = sred[0] + sred[1] + sred[2] + sred[3];
  float inv = 1.f / s;
  f16x8 p;
  #pragma unroll
  for (int j = 0; j < 8; ++j) p[j] = (f16)(e[j] * inv);
  Pr[tid] = p;
}

// ---------------- host launcher ----------------
extern "C" void kernel_launch(void* const* d_in, const int* in_sizes, int n_in,
                              void* d_out, int out_size, void* d_ws, size_t ws_size,
                              hipStream_t stream) {
  const float* qs   = (const float*)d_in[0];   // [8,2048,512]
  const float* kv   = (const float*)d_in[1];   // [8,2048,768]
  const float* Wq   = (const float*)d_in[2];
  const float* bq   = (const float*)d_in[3];
  const float* gq   = (const float*)d_in[4];
  const float* beq  = (const float*)d_in[5];
  const float* Wk   = (const float*)d_in[6];
  const float* bk   = (const float*)d_in[7];
  const float* gk   = (const float*)d_in[8];
  const float* bek  = (const float*)d_in[9];
  const float* Wv   = (const float*)d_in[10];
  const float* bv   = (const float*)d_in[11];
  const float* gv   = (const float*)d_in[12];
  const float* bev  = (const float*)d_in[13];
  float* out = (float*)d_out;

  // ---- workspace layout (peak 119,537,664 B ~= 114 MB) ----
  char* ws = (char*)d_ws;
  f16* q16  = (f16*)(ws + 0);            // 16,777,216 B  [8,2048,512]
  f16* k16  = (f16*)(ws + 16777216);     // 16,777,216 B  [8,2048,512]
  f16* vt   = (f16*)(ws + 33554432);     // 16,777,216 B  [8,512,2048]
  f16* Wqt  = (f16*)(ws + 50331648);     //    524,288 B  [512][512]
  f16* Wkt  = (f16*)(ws + 50855936);     //    786,432 B  [512][768]
  f16* Wvt  = (f16*)(ws + 51642368);     //    786,432 B  [512][768]
  f16* S    = (f16*)(ws + 52428800);     // 67,108,864 B  [8,2048,2048] f16
                                         // ends 119,537,664 B

  // K0: weight transpose+cast (small)
  cast_transpose<<<1024, 256, 0, stream>>>(Wq, Wqt, 512, 512);
  cast_transpose<<<1536, 256, 0, stream>>>(Wk, Wkt, 768, 512);
  cast_transpose<<<1536, 256, 0, stream>>>(Wv, Wvt, 768, 512);

  // K1: fused projections + LN (768 blocks = 3 projections x 256 tiles)
  proj_ln<<<768, 512, 0, stream>>>(qs, kv, Wqt, Wkt, Wvt,
                                   bq, gq, beq, bk, gk, bek, bv, gv, bev,
                                   q16, k16, vt);

  // K2: S[b,l,L] = sum_c k[b,l,c] * q[b,L,c]   (NT, f16 out)
  gemm_nt<false, f16><<<2048, 256, 0, stream>>>(
      k16, q16, S, nullptr,
      /*K=*/512, /*tilesM=*/16, /*tilesN=*/16, /*N=*/2048,
      (size_t)2048 * 512, (size_t)2048 * 512, (size_t)2048 * 2048);

  // K3: row softmax over L, in-place f16
  softmax_rows<<<16384, 256, 0, stream>>>(S);

  // K4: out[b,l,c] = sum_L P[b,l,L] * vt[b,c,L] + qs[b,l,c]
  gemm_nt<true, float><<<512, 256, 0, stream>>>(
      S, vt, out, qs,
      /*K=*/2048, /*tilesM=*/16, /*tilesN=*/4, /*N=*/512,
      (size_t)2048 * 2048, (size_t)512 * 2048, (size_t)2048 * 512);
}